// Round 1
// baseline (159.967 us; speedup 1.0000x reference)
//
#include <hip/hip_runtime.h>
#include <hip/hip_bf16.h>

#define B_DIM 8192
#define D_DIM 256

constexpr float INV_T  = 14.285714285714286f;  // 1/0.07
constexpr float M_CONST = 14.285714285714286f; // fixed logsumexp shift (sim <= 1/T)

typedef __bf16 bf16x8 __attribute__((ext_vector_type(8)));
typedef float  f32x4  __attribute__((ext_vector_type(4)));

__device__ inline unsigned short f2bf(float f) {
    union { float f; unsigned u; } x; x.f = f;
    unsigned r = x.u + 0x7fffu + ((x.u >> 16) & 1u);  // RNE
    return (unsigned short)(r >> 16);
}

// Kernel 1: q = normalize(h+r), t = normalize(t), cast to bf16 into ws.
// One wave per row-task; 16384 tasks (8192 q + 8192 t).
__global__ __launch_bounds__(256) void norm_kernel(
    const float* __restrict__ h, const float* __restrict__ r,
    const float* __restrict__ t,
    unsigned short* __restrict__ qws, unsigned short* __restrict__ tws)
{
    int wave = threadIdx.x >> 6;
    int lane = threadIdx.x & 63;
    int task = blockIdx.x * 4 + wave;
    bool isQ = task < B_DIM;
    int row  = isQ ? task : task - B_DIM;

    float4 v;
    if (isQ) {
        float4 a = ((const float4*)h)[row * 64 + lane];
        float4 b = ((const float4*)r)[row * 64 + lane];
        v = make_float4(a.x + b.x, a.y + b.y, a.z + b.z, a.w + b.w);
    } else {
        v = ((const float4*)t)[row * 64 + lane];
    }
    float s = v.x * v.x + v.y * v.y + v.z * v.z + v.w * v.w;
#pragma unroll
    for (int off = 32; off; off >>= 1) s += __shfl_xor(s, off, 64);
    float scale = 1.0f / fmaxf(sqrtf(s), 1e-12f);

    ushort4 o;
    o.x = f2bf(v.x * scale);
    o.y = f2bf(v.y * scale);
    o.z = f2bf(v.z * scale);
    o.w = f2bf(v.w * scale);
    ushort4* dst = (ushort4*)(isQ ? qws : tws);
    dst[row * 64 + lane] = o;
}

// Kernel 2: fused GEMM (q · t^T / T) + exp-sum per row + diagonal extraction.
// Block tile: 64 rows x (2048-col chunk, iterated in 64-col tiles).
// Grid: 128 row-blocks x 4 col-chunks = 512 blocks.
// LDS row stride 528 B (= 512 data + 16 pad) -> 2-way bank conflict (free).
__global__ __launch_bounds__(256) void gemm_lse_kernel(
    const uint4* __restrict__ qws, const uint4* __restrict__ tws,
    float* __restrict__ rowsum, float* __restrict__ pos)
{
    __shared__ __align__(16) unsigned char smem[2 * 64 * 528];
    unsigned char* ldsQ = smem;
    unsigned char* ldsT = smem + 64 * 528;

    const int tid  = threadIdx.x;
    const int lane = tid & 63;
    const int w    = tid >> 6;
    const int quad = lane >> 4;
    const int l15  = lane & 15;

    const int rb    = blockIdx.x & 127;   // row block
    const int nc    = blockIdx.x >> 7;    // col chunk (consecutive blocks share t chunk)
    const int row0  = rb * 64;
    const int ncol0 = nc * 2048;

    // stage q rows [row0, row0+64): 64 rows x 512 B, 16 B/thread/iter
#pragma unroll
    for (int it = 0; it < 8; ++it) {
        int c2 = it * 256 + tid;
        int rr = c2 >> 5, cc = c2 & 31;
        *(uint4*)(ldsQ + rr * 528 + cc * 16) = qws[(row0 + rr) * 32 + cc];
    }

    float rowacc[4] = {0.f, 0.f, 0.f, 0.f};
    const int myrow = row0 + w * 16 + quad * 4;  // + i

    for (int nt = 0; nt < 32; ++nt) {
        const int n0 = ncol0 + nt * 64;
        __syncthreads();  // previous tile's compute done (and q staged on iter 0)
#pragma unroll
        for (int it = 0; it < 8; ++it) {
            int c2 = it * 256 + tid;
            int rr = c2 >> 5, cc = c2 & 31;
            *(uint4*)(ldsT + rr * 528 + cc * 16) = tws[(n0 + rr) * 32 + cc];
        }
        __syncthreads();

        f32x4 acc[4] = {};
        const unsigned char* aRow  = ldsQ + (w * 16 + l15) * 528 + quad * 16;
        const unsigned char* bRow0 = ldsT + l15 * 528 + quad * 16;
#pragma unroll
        for (int ks = 0; ks < 8; ++ks) {
            bf16x8 a = *(const bf16x8*)(aRow + ks * 64);
#pragma unroll
            for (int ct = 0; ct < 4; ++ct) {
                bf16x8 b = *(const bf16x8*)(bRow0 + ct * 16 * 528 + ks * 64);
                acc[ct] = __builtin_amdgcn_mfma_f32_16x16x32_bf16(a, b, acc[ct], 0, 0, 0);
            }
        }

        // epilogue: sim = acc/T; accumulate exp(sim - M) per row; grab diagonal.
#pragma unroll
        for (int i = 0; i < 4; ++i) {
            const int grow = myrow + i;
            float s = 0.f;
#pragma unroll
            for (int ct = 0; ct < 4; ++ct) {
                float sim = acc[ct][i] * INV_T;
                int gcol = n0 + ct * 16 + l15;
                if (gcol == grow) pos[grow] = sim;
                s += __expf(sim - M_CONST);
            }
            s += __shfl_xor(s, 1, 64);
            s += __shfl_xor(s, 2, 64);
            s += __shfl_xor(s, 4, 64);
            s += __shfl_xor(s, 8, 64);
            rowacc[i] += s;
        }
    }

    if (l15 == 0) {
#pragma unroll
        for (int i = 0; i < 4; ++i)
            atomicAdd(&rowsum[myrow + i], rowacc[i]);
    }
}

// Kernel 3: loss = mean( M + log(rowsum) - pos )
__global__ __launch_bounds__(256) void finalize_kernel(
    const float* __restrict__ rowsum, const float* __restrict__ pos,
    float* __restrict__ out)
{
    float lsum = 0.f;
    for (int r = threadIdx.x; r < B_DIM; r += 256)
        lsum += M_CONST + logf(rowsum[r]) - pos[r];
#pragma unroll
    for (int off = 32; off; off >>= 1) lsum += __shfl_xor(lsum, off, 64);
    __shared__ float wsum[4];
    if ((threadIdx.x & 63) == 0) wsum[threadIdx.x >> 6] = lsum;
    __syncthreads();
    if (threadIdx.x == 0)
        out[0] = (wsum[0] + wsum[1] + wsum[2] + wsum[3]) / (float)B_DIM;
}

extern "C" void kernel_launch(void* const* d_in, const int* in_sizes, int n_in,
                              void* d_out, int out_size, void* d_ws, size_t ws_size,
                              hipStream_t stream)
{
    const float* h = (const float*)d_in[0];
    const float* r = (const float*)d_in[1];
    const float* t = (const float*)d_in[2];

    unsigned char* ws = (unsigned char*)d_ws;
    unsigned short* qws = (unsigned short*)ws;                        // 4 MB
    unsigned short* tws = (unsigned short*)(ws + 4u * 1024 * 1024);   // 4 MB
    float* rowsum = (float*)(ws + 8u * 1024 * 1024);                  // 32 KB
    float* pos    = (float*)(ws + 8u * 1024 * 1024 + 32u * 1024);     // 32 KB

    hipMemsetAsync(rowsum, 0, B_DIM * sizeof(float), stream);
    norm_kernel<<<4096, 256, 0, stream>>>(h, r, t, qws, tws);
    gemm_lse_kernel<<<512, 256, 0, stream>>>((const uint4*)qws, (const uint4*)tws,
                                             rowsum, pos);
    finalize_kernel<<<1, 256, 0, stream>>>(rowsum, pos, (float*)d_out);
}